// Round 1
// baseline (6667.081 us; speedup 1.0000x reference)
//
#include <hip/hip_runtime.h>
#include <hip/hip_bf16.h>

// Problem dims (fixed by reference)
#define B_  256
#define L_  64
#define DI_ 2048
#define T_  32
#define DT_ 512
#define U_  512
#define A_  512
#define N3U 1536   // 3*U

// ---------------------------------------------------------------------------
// Generic fp32 tiled GEMM: C[M,N] = A[M,K] @ B[K,N] (+ bias[N] if bias!=null)
// Row-major everything. M%64==0, N%64==0, K%16==0 for all our shapes.
// 64x64 tile, BK=16, 256 threads, 4x4 micro-tile per thread.
// ---------------------------------------------------------------------------
#define BM 64
#define BN 64
#define BK 16

__global__ __launch_bounds__(256) void gemm_f32(
    const float* __restrict__ A, const float* __restrict__ Bm,
    const float* __restrict__ bias, float* __restrict__ C,
    int M, int N, int K) {
  __shared__ float As[BK][BM];   // transposed A tile
  __shared__ float Bs[BK][BN];
  const int tid = threadIdx.x;
  const int tx = tid & 15;       // col group 0..15
  const int ty = tid >> 4;       // row group 0..15
  const long bm = (long)blockIdx.y * BM;
  const long bn = (long)blockIdx.x * BN;

  // staging load indices
  const int arow = tid >> 2;         // 0..63
  const int acol = (tid & 3) * 4;    // 0,4,8,12
  const int brow = tid >> 4;         // 0..15
  const int bcol = (tid & 15) * 4;   // 0..60

  float acc[4][4] = {};

  for (int k0 = 0; k0 < K; k0 += BK) {
    float4 av = *(const float4*)(A + (bm + arow) * (long)K + k0 + acol);
    float4 bv = *(const float4*)(Bm + (long)(k0 + brow) * N + bn + bcol);
    As[acol + 0][arow] = av.x;
    As[acol + 1][arow] = av.y;
    As[acol + 2][arow] = av.z;
    As[acol + 3][arow] = av.w;
    *(float4*)&Bs[brow][bcol] = bv;
    __syncthreads();
#pragma unroll
    for (int kk = 0; kk < BK; ++kk) {
      float a[4], b[4];
#pragma unroll
      for (int i = 0; i < 4; ++i) a[i] = As[kk][ty * 4 + i];
#pragma unroll
      for (int j = 0; j < 4; ++j) b[j] = Bs[kk][tx * 4 + j];
#pragma unroll
      for (int i = 0; i < 4; ++i)
#pragma unroll
        for (int j = 0; j < 4; ++j) acc[i][j] += a[i] * b[j];
    }
    __syncthreads();
  }

#pragma unroll
  for (int i = 0; i < 4; ++i) {
    long r = bm + ty * 4 + i;
    long c0 = bn + tx * 4;
    float4 v;
    v.x = acc[i][0]; v.y = acc[i][1]; v.z = acc[i][2]; v.w = acc[i][3];
    if (bias) {
      v.x += bias[c0 + 0]; v.y += bias[c0 + 1];
      v.z += bias[c0 + 2]; v.w += bias[c0 + 3];
    }
    *(float4*)(C + r * (long)N + c0) = v;
  }
}

// ---------------------------------------------------------------------------
// zero-init (ws is poisoned 0xAA before every launch)
// ---------------------------------------------------------------------------
__global__ void zero_f32(float* __restrict__ p, int n) {
  int i = blockIdx.x * 256 + threadIdx.x;
  if (i < n) p[i] = 0.f;
}

// ---------------------------------------------------------------------------
// Attention scores + softmax.
// score[b,l] = sum_a tanh(img_proj[b,l,a] + hproj[b,a]) * v[a]
// attw[b,:]  = softmax over l (att_v_bias cancels in softmax — skipped)
// grid: B blocks of 256 threads (4 waves; each wave reduces 16 l's)
// ---------------------------------------------------------------------------
__global__ __launch_bounds__(256) void attn_score(
    const float* __restrict__ img_proj,  // [B,L,A]
    const float* __restrict__ hproj,     // [B,A]
    const float* __restrict__ v,         // [A]
    float* __restrict__ attw) {          // [B,L]
  const int b = blockIdx.x;
  const int tid = threadIdx.x;
  const int lane = tid & 63;
  const int wave = tid >> 6;
  __shared__ float hp[A_];
  __shared__ float vv[A_];
  __shared__ float sc[L_];

  for (int i = tid; i < A_; i += 256) {
    hp[i] = hproj[b * A_ + i];
    vv[i] = v[i];
  }
  __syncthreads();

  for (int l = wave; l < L_; l += 4) {
    const float* ip = img_proj + ((long)b * L_ + l) * A_;
    float s = 0.f;
    for (int a = lane; a < A_; a += 64) {
      float x = ip[a] + hp[a];
      x = fminf(fmaxf(x, -15.f), 15.f);
      float e = __expf(2.f * x);
      float t = (e - 1.f) / (e + 1.f);   // tanh(x)
      s += t * vv[a];
    }
#pragma unroll
    for (int off = 32; off; off >>= 1) s += __shfl_down(s, off);
    if (lane == 0) sc[l] = s;
  }
  __syncthreads();

  if (tid < 64) {
    float x = sc[tid];
    float m = x;
#pragma unroll
    for (int off = 32; off; off >>= 1) m = fmaxf(m, __shfl_xor(m, off));
    float e = __expf(x - m);
    float s = e;
#pragma unroll
    for (int off = 32; off; off >>= 1) s += __shfl_xor(s, off);
    attw[b * L_ + tid] = e / s;
  }
}

// ---------------------------------------------------------------------------
// Per-step combine + GRU gates.
// mx[b,n]  = sum_l attw[b,l] * imgW[b,l,n] + text_proj[b,t,n]
// z = sig(mx_z + mi_z); r = sig(mx_r + mi_r); hh = tanh(mx_h + r*mi_h)
// h_new = z*h + (1-z)*hh ; write h and out[b,t,:]
// grid: B blocks of 256 threads
// ---------------------------------------------------------------------------
__global__ __launch_bounds__(256) void gru_step(
    const float* __restrict__ imgW,       // [B,L,3U]
    const float* __restrict__ attw,       // [B,L]
    const float* __restrict__ text_proj,  // [B,T,3U]
    const float* __restrict__ mi,         // [B,3U]
    float* __restrict__ h,                // [B,U] in/out
    float* __restrict__ out,              // [B,T,U]
    int t) {
  const int b = blockIdx.x;
  const int tid = threadIdx.x;
  __shared__ float aw[L_];
  __shared__ float mx[N3U];

  if (tid < L_) aw[tid] = attw[b * L_ + tid];
  __syncthreads();

  const float* iw = imgW + (long)b * L_ * N3U;
  const float* tp = text_proj + ((long)b * T_ + t) * N3U;
#pragma unroll
  for (int i = 0; i < 6; ++i) {
    const int n = tid + 256 * i;
    float s = 0.f;
#pragma unroll 8
    for (int l = 0; l < L_; ++l) s += aw[l] * iw[l * N3U + n];
    mx[n] = s + tp[n];
  }
  __syncthreads();

  const float* mib = mi + b * N3U;
  const float* hb = h + b * U_;
#pragma unroll
  for (int i = 0; i < 2; ++i) {
    const int u = tid + 256 * i;
    float z = 1.f / (1.f + __expf(-(mx[u] + mib[u])));
    float r = 1.f / (1.f + __expf(-(mx[U_ + u] + mib[U_ + u])));
    float xh = mx[2 * U_ + u] + r * mib[2 * U_ + u];
    xh = fminf(fmaxf(xh, -15.f), 15.f);
    float e = __expf(2.f * xh);
    float hh = (e - 1.f) / (e + 1.f);    // tanh
    float hn = z * hb[u] + (1.f - z) * hh;
    h[b * U_ + u] = hn;
    out[((long)b * T_ + t) * U_ + u] = hn;
  }
}

// ---------------------------------------------------------------------------
// launch
// ---------------------------------------------------------------------------
extern "C" void kernel_launch(void* const* d_in, const int* in_sizes, int n_in,
                              void* d_out, int out_size, void* d_ws, size_t ws_size,
                              hipStream_t stream) {
  const float* img        = (const float*)d_in[0];   // [B,L,DI]
  const float* text       = (const float*)d_in[1];   // [B,T,DT]
  const float* kern       = (const float*)d_in[2];   // [DT+DI, 3U]
  const float* input_bias = (const float*)d_in[3];   // [3U]
  const float* rec_kern   = (const float*)d_in[4];   // [U,3U]
  const float* rec_bias   = (const float*)d_in[5];   // [3U]
  const float* att_img_k  = (const float*)d_in[6];   // [DI,A]
  const float* att_img_b  = (const float*)d_in[7];   // [A]
  const float* att_hid_k  = (const float*)d_in[8];   // [U,A]
  const float* att_hid_b  = (const float*)d_in[9];   // [A]
  const float* att_v_k    = (const float*)d_in[10];  // [A,1]
  // d_in[11] = att_v_bias — cancels in softmax, unused.
  float* out = (float*)d_out;

  // workspace layout (floats). Total ~46.8M floats ≈ 187 MB.
  float* ws = (float*)d_ws;
  float* img_proj  = ws;                         // B*L*A      = 8,388,608
  float* imgW      = img_proj + (long)B_*L_*A_;  // B*L*3U     = 25,165,824
  float* text_proj = imgW + (long)B_*L_*N3U;     // B*T*3U     = 12,582,912
  float* h         = text_proj + (long)B_*T_*N3U;// B*U        = 131,072
  float* hproj     = h + B_*U_;                  // B*A        = 131,072
  float* mi        = hproj + B_*A_;              // B*3U       = 393,216
  float* attw      = mi + B_*N3U;                // B*L        = 16,384

  dim3 blk(256);

  // h0 = 0
  zero_f32<<<dim3((B_*U_ + 255) / 256), blk, 0, stream>>>(h, B_*U_);

  // Precompute (independent of the recurrence):
  // img_proj = img @ att_img_kernel + att_img_bias     [16384 x 2048 x 512]
  gemm_f32<<<dim3(A_/BN, (B_*L_)/BM), blk, 0, stream>>>(
      img, att_img_k, att_img_b, img_proj, B_*L_, A_, DI_);
  // imgW = img @ kernel[DT:,:]                         [16384 x 2048 x 1536]
  gemm_f32<<<dim3(N3U/BN, (B_*L_)/BM), blk, 0, stream>>>(
      img, kern + (long)DT_ * N3U, nullptr, imgW, B_*L_, N3U, DI_);
  // text_proj = text @ kernel[:DT,:] + input_bias      [8192 x 512 x 1536]
  gemm_f32<<<dim3(N3U/BN, (B_*T_)/BM), blk, 0, stream>>>(
      text, kern, input_bias, text_proj, B_*T_, N3U, DT_);

  // Sequential recurrence
  for (int t = 0; t < T_; ++t) {
    // hproj = h @ att_hidden_kernel + att_hidden_bias  [256 x 512 x 512]
    gemm_f32<<<dim3(A_/BN, B_/BM), blk, 0, stream>>>(
        h, att_hid_k, att_hid_b, hproj, B_, A_, U_);
    // mi = h @ recurrent_kernel + recurrent_bias       [256 x 512 x 1536]
    gemm_f32<<<dim3(N3U/BN, B_/BM), blk, 0, stream>>>(
        h, rec_kern, rec_bias, mi, B_, N3U, U_);
    attn_score<<<dim3(B_), blk, 0, stream>>>(img_proj, hproj, att_v_k, attw);
    gru_step<<<dim3(B_), blk, 0, stream>>>(imgW, attw, text_proj, mi, h, out, t);
  }
}

// Round 3
// 3261.513 us; speedup vs baseline: 2.0442x; 2.0442x over previous
//
#include <hip/hip_runtime.h>
#include <hip/hip_bf16.h>

// Problem dims (fixed by reference)
#define B_  256
#define L_  64
#define DI_ 2048
#define T_  32
#define DT_ 512
#define U_  512
#define A_  512
#define N3U 1536   // 3*U

typedef short short8 __attribute__((ext_vector_type(8)));   // 8 bf16 = 4 VGPRs
typedef float floatx4 __attribute__((ext_vector_type(4)));  // mfma acc

// fp32 -> bf16 round-to-nearest-even
__device__ __forceinline__ unsigned short f2bf(float f) {
  unsigned int u = __float_as_uint(f);
  u += 0x7fffu + ((u >> 16) & 1u);
  return (unsigned short)(u >> 16);
}
__device__ __forceinline__ float bf2f(unsigned short s) {
  return __uint_as_float(((unsigned int)s) << 16);
}
__device__ __forceinline__ float fast_tanh(float x) {
  x = fminf(fmaxf(x, -15.f), 15.f);
  float e = __expf(2.f * x);
  return (e - 1.f) / (e + 1.f);
}

// ---------------------------------------------------------------------------
// MFMA GEMM with fused A-conversion:
//   C[M,N] = A[M,K](fp32) @ Bt[N,K](bf16)^T (+bias), out fp32 or bf16.
// A is converted fp32->bf16 during LDS staging (no separate conversion pass,
// no aliased scratch buffers). 128x128 tile, BK=32, 256 threads = 4 waves,
// each wave computes a 64x64 sub-tile via 4x4 mfma_f32_16x16x32_bf16.
// LDS row stride 40 ushorts (pad 8): fragment ds_read_b128 at free 2-way.
// M%128==0, N%128==0, K%32==0 for all our shapes.
// ---------------------------------------------------------------------------
__global__ __launch_bounds__(256) void gemm_a32_bt16_mfma(
    const float* __restrict__ A, const unsigned short* __restrict__ Bt,
    const float* __restrict__ bias, void* __restrict__ Cout,
    int M, int N, int K, int out_bf16) {
  __shared__ unsigned short As[128][40];
  __shared__ unsigned short Bs[128][40];
  const int tid  = threadIdx.x;
  const int wave = tid >> 6;
  const int lane = tid & 63;
  const int quad = lane >> 4;
  const int lr   = lane & 15;
  const int wrow = (wave >> 1) * 64;
  const int wcol = (wave & 1) * 64;
  const size_t bm = (size_t)blockIdx.y * 128;
  const size_t bn = (size_t)blockIdx.x * 128;

  const int sr = tid >> 2;          // staging row 0..63
  const int sc = (tid & 3) * 8;     // staging col (ushorts) 0,8,16,24

  floatx4 acc[4][4] = {};

  for (int k0 = 0; k0 < K; k0 += 32) {
#pragma unroll
    for (int it = 0; it < 2; ++it) {
      const int row = sr + it * 64;
      // A: fp32 -> bf16 convert-on-stage (8 floats -> 8 bf16)
      const float* ap = A + (bm + row) * (size_t)K + k0 + sc;
      float4 a0 = *(const float4*)(ap);
      float4 a1 = *(const float4*)(ap + 4);
      short8 pk;
      pk[0] = (short)f2bf(a0.x); pk[1] = (short)f2bf(a0.y);
      pk[2] = (short)f2bf(a0.z); pk[3] = (short)f2bf(a0.w);
      pk[4] = (short)f2bf(a1.x); pk[5] = (short)f2bf(a1.y);
      pk[6] = (short)f2bf(a1.z); pk[7] = (short)f2bf(a1.w);
      *(short8*)&As[row][sc] = pk;
      // B: already bf16, straight 16B copy
      *(float4*)&Bs[row][sc] = *(const float4*)(Bt + (bn + row) * (size_t)K + k0 + sc);
    }
    __syncthreads();
    short8 af[4], bf[4];
#pragma unroll
    for (int mi = 0; mi < 4; ++mi) af[mi] = *(const short8*)&As[wrow + mi * 16 + lr][quad * 8];
#pragma unroll
    for (int ni = 0; ni < 4; ++ni) bf[ni] = *(const short8*)&Bs[wcol + ni * 16 + lr][quad * 8];
#pragma unroll
    for (int mi = 0; mi < 4; ++mi)
#pragma unroll
      for (int ni = 0; ni < 4; ++ni)
        acc[mi][ni] = __builtin_amdgcn_mfma_f32_16x16x32_bf16(af[mi], bf[ni], acc[mi][ni], 0, 0, 0);
    __syncthreads();
  }

  float* outf = (float*)Cout;
  unsigned short* outb = (unsigned short*)Cout;
#pragma unroll
  for (int mi = 0; mi < 4; ++mi) {
#pragma unroll
    for (int ni = 0; ni < 4; ++ni) {
      const size_t row0 = bm + wrow + mi * 16 + quad * 4;
      const size_t col  = bn + wcol + ni * 16 + lr;
      const float bsum = bias ? bias[col] : 0.f;
#pragma unroll
      for (int reg = 0; reg < 4; ++reg) {
        const float v = acc[mi][ni][reg] + bsum;
        if (out_bf16) outb[(row0 + reg) * (size_t)N + col] = f2bf(v);
        else          outf[(row0 + reg) * (size_t)N + col] = v;
      }
    }
  }
}

// ---------------------------------------------------------------------------
// fp32 tiled GEMM (per-step h GEMM). 64x64 tile, BK=16.
// ---------------------------------------------------------------------------
#define BM 64
#define BN 64
#define BK 16
__global__ __launch_bounds__(256) void gemm_f32(
    const float* __restrict__ A, const float* __restrict__ Bm,
    const float* __restrict__ bias, float* __restrict__ C,
    int M, int N, int K) {
  __shared__ float As[BK][BM];
  __shared__ float Bs[BK][BN];
  const int tid = threadIdx.x;
  const int tx = tid & 15;
  const int ty = tid >> 4;
  const long bm = (long)blockIdx.y * BM;
  const long bn = (long)blockIdx.x * BN;
  const int arow = tid >> 2;
  const int acol = (tid & 3) * 4;
  const int brow = tid >> 4;
  const int bcol = (tid & 15) * 4;
  float acc[4][4] = {};
  for (int k0 = 0; k0 < K; k0 += BK) {
    float4 av = *(const float4*)(A + (bm + arow) * (long)K + k0 + acol);
    float4 bv = *(const float4*)(Bm + (long)(k0 + brow) * N + bn + bcol);
    As[acol + 0][arow] = av.x;
    As[acol + 1][arow] = av.y;
    As[acol + 2][arow] = av.z;
    As[acol + 3][arow] = av.w;
    *(float4*)&Bs[brow][bcol] = bv;
    __syncthreads();
#pragma unroll
    for (int kk = 0; kk < BK; ++kk) {
      float a[4], b[4];
#pragma unroll
      for (int i = 0; i < 4; ++i) a[i] = As[kk][ty * 4 + i];
#pragma unroll
      for (int j = 0; j < 4; ++j) b[j] = Bs[kk][tx * 4 + j];
#pragma unroll
      for (int i = 0; i < 4; ++i)
#pragma unroll
        for (int j = 0; j < 4; ++j) acc[i][j] += a[i] * b[j];
    }
    __syncthreads();
  }
#pragma unroll
  for (int i = 0; i < 4; ++i) {
    long r = bm + ty * 4 + i;
    long c0 = bn + tx * 4;
    float4 v;
    v.x = acc[i][0]; v.y = acc[i][1]; v.z = acc[i][2]; v.w = acc[i][3];
    if (bias) {
      v.x += bias[c0 + 0]; v.y += bias[c0 + 1];
      v.z += bias[c0 + 2]; v.w += bias[c0 + 3];
    }
    *(float4*)(C + r * (long)N + c0) = v;
  }
}

// ---------------------------------------------------------------------------
// small helpers
// ---------------------------------------------------------------------------
__global__ void zero_f32(float* __restrict__ p, int n) {
  int i = blockIdx.x * 256 + threadIdx.x;
  if (i < n) p[i] = 0.f;
}

// in[K,N] fp32 -> out[N,K] bf16 (tiled transpose). K%32==0, N%32==0.
__global__ __launch_bounds__(256) void transpose_f32_bf16(
    const float* __restrict__ in, unsigned short* __restrict__ outp, int K, int N) {
  __shared__ unsigned short tile[32][33];
  const int tid = threadIdx.x;
  const int tx = tid & 31, ty = tid >> 5;  // ty 0..7
  const int k0 = blockIdx.y * 32, n0 = blockIdx.x * 32;
#pragma unroll
  for (int i = 0; i < 4; ++i) {
    const int kk = ty + i * 8;
    tile[tx][kk] = f2bf(in[(size_t)(k0 + kk) * N + n0 + tx]);
  }
  __syncthreads();
#pragma unroll
  for (int i = 0; i < 4; ++i) {
    const int nn = ty + i * 8;
    outp[(size_t)(n0 + nn) * K + k0 + tx] = tile[nn][tx];
  }
}

// Wcat[512, 2048] = [att_hid_k (512x512) | rec_kern (512x1536)], bcat likewise
__global__ __launch_bounds__(256) void build_wcat(
    const float* __restrict__ ahk, const float* __restrict__ ahb,
    const float* __restrict__ rk, const float* __restrict__ rb,
    float* __restrict__ Wcat, float* __restrict__ bcat) {
  const int row = blockIdx.x;
  const int tid = threadIdx.x;
  for (int c = tid; c < A_; c += 256) Wcat[row * 2048 + c] = ahk[row * A_ + c];
  for (int c = tid; c < N3U; c += 256) Wcat[row * 2048 + A_ + c] = rk[row * N3U + c];
  if (row == 0) {
    for (int c = tid; c < A_; c += 256) bcat[c] = ahb[c];
    for (int c = tid; c < N3U; c += 256) bcat[A_ + c] = rb[c];
  }
}

// ---------------------------------------------------------------------------
// Attention scores + softmax. img_proj is bf16. hproj = hm cols [0,512).
// ---------------------------------------------------------------------------
__global__ __launch_bounds__(256) void attn_score(
    const unsigned short* __restrict__ img_proj,  // [B,L,A] bf16
    const float* __restrict__ hm,                 // [B,2048]
    const float* __restrict__ v,                  // [A]
    float* __restrict__ attw) {                   // [B,L]
  const int b = blockIdx.x;
  const int tid = threadIdx.x;
  const int lane = tid & 63;
  const int wave = tid >> 6;
  __shared__ float hp[A_];
  __shared__ float vv[A_];
  __shared__ float sc[L_];
  for (int i = tid; i < A_; i += 256) {
    hp[i] = hm[b * 2048 + i];
    vv[i] = v[i];
  }
  __syncthreads();
  for (int l = wave; l < L_; l += 4) {
    const unsigned short* ip = img_proj + ((size_t)b * L_ + l) * A_;
    float s = 0.f;
    for (int a = lane; a < A_; a += 64) {
      s += fast_tanh(bf2f(ip[a]) + hp[a]) * vv[a];
    }
#pragma unroll
    for (int off = 32; off; off >>= 1) s += __shfl_down(s, off);
    if (lane == 0) sc[l] = s;
  }
  __syncthreads();
  if (tid < 64) {
    float x = sc[tid];
    float m = x;
#pragma unroll
    for (int off = 32; off; off >>= 1) m = fmaxf(m, __shfl_xor(m, off));
    float e = __expf(x - m);
    float s = e;
#pragma unroll
    for (int off = 32; off; off >>= 1) s += __shfl_xor(s, off);
    attw[b * L_ + tid] = e / s;
  }
}

// ---------------------------------------------------------------------------
// Per-step combine + GRU gates. 512 threads: thread u owns x_z/x_r/x_h for u.
// ---------------------------------------------------------------------------
__global__ __launch_bounds__(512) void gru_step(
    const unsigned short* __restrict__ imgW,  // [B,L,3U] bf16
    const float* __restrict__ attw,           // [B,L]
    const float* __restrict__ text_proj,      // [B,T,3U]
    const float* __restrict__ hm,             // [B,2048]; mi = cols [512,2048)
    float* __restrict__ h,                    // [B,U]
    float* __restrict__ out,                  // [B,T,U]
    int t) {
  const int b = blockIdx.x;
  const int u = threadIdx.x;  // 0..511
  __shared__ float aw[L_];
  if (u < L_) aw[u] = attw[b * L_ + u];
  __syncthreads();
  const unsigned short* iw = imgW + (size_t)b * L_ * N3U + u;
  float s0 = 0.f, s1 = 0.f, s2 = 0.f;
#pragma unroll 8
  for (int l = 0; l < L_; ++l) {
    const float a = aw[l];
    const unsigned short* p = iw + l * N3U;
    s0 += a * bf2f(p[0]);
    s1 += a * bf2f(p[512]);
    s2 += a * bf2f(p[1024]);
  }
  const float* tp  = text_proj + ((size_t)b * T_ + t) * N3U;
  const float* mib = hm + b * 2048 + 512;
  const float xz = s0 + tp[u]        + mib[u];
  const float xr = s1 + tp[512 + u]  + mib[512 + u];
  const float xh = s2 + tp[1024 + u];
  const float rh = mib[1024 + u];
  const float z = 1.f / (1.f + __expf(-xz));
  const float r = 1.f / (1.f + __expf(-xr));
  const float hh = fast_tanh(xh + r * rh);
  const float hn = z * h[b * U_ + u] + (1.f - z) * hh;
  h[b * U_ + u] = hn;
  out[((size_t)b * T_ + t) * U_ + u] = hn;
}

// ---------------------------------------------------------------------------
// launch
// ---------------------------------------------------------------------------
extern "C" void kernel_launch(void* const* d_in, const int* in_sizes, int n_in,
                              void* d_out, int out_size, void* d_ws, size_t ws_size,
                              hipStream_t stream) {
  const float* img        = (const float*)d_in[0];   // [B,L,DI]
  const float* text       = (const float*)d_in[1];   // [B,T,DT]
  const float* kern       = (const float*)d_in[2];   // [DT+DI, 3U]
  const float* input_bias = (const float*)d_in[3];   // [3U]
  const float* rec_kern   = (const float*)d_in[4];   // [U,3U]
  const float* rec_bias   = (const float*)d_in[5];   // [3U]
  const float* att_img_k  = (const float*)d_in[6];   // [DI,A]
  const float* att_img_b  = (const float*)d_in[7];   // [A]
  const float* att_hid_k  = (const float*)d_in[8];   // [U,A]
  const float* att_hid_b  = (const float*)d_in[9];   // [A]
  const float* att_v_k    = (const float*)d_in[10];  // [A,1]
  // d_in[11] = att_v_bias — cancels in softmax.
  float* out = (float*)d_out;

  // workspace layout (bytes, 256-aligned). NO ALIASING. ~134 MB total.
  char* ws = (char*)d_ws;
  size_t off = 0;
  auto alloc = [&](size_t bytes) { char* p = ws + off; off += (bytes + 255) & ~(size_t)255; return p; };
  unsigned short* img_proj = (unsigned short*)alloc((size_t)B_*L_*A_*2);   // 16.8 MB bf16
  unsigned short* imgW     = (unsigned short*)alloc((size_t)B_*L_*N3U*2);  // 50.3 MB bf16
  float*          text_proj= (float*)         alloc((size_t)B_*T_*N3U*4);  // 50.3 MB fp32
  unsigned short* wt1      = (unsigned short*)alloc((size_t)A_*DI_*2);     // att_img_k^T
  unsigned short* wt2      = (unsigned short*)alloc((size_t)N3U*DI_*2);    // kern[DT:]^T
  unsigned short* wt3      = (unsigned short*)alloc((size_t)N3U*DT_*2);    // kern[:DT]^T
  float*          Wcat     = (float*)         alloc((size_t)U_*2048*4);    // 4.2 MB
  float*          bcat     = (float*)         alloc(2048*4);
  float*          h        = (float*)         alloc((size_t)B_*U_*4);
  float*          hm       = (float*)         alloc((size_t)B_*2048*4);
  float*          attw     = (float*)         alloc((size_t)B_*L_*4);

  dim3 blk(256);

  zero_f32<<<dim3((B_*U_ + 255) / 256), blk, 0, stream>>>(h, B_*U_);

  // one-time weight transposes (fp32 -> bf16^T)
  transpose_f32_bf16<<<dim3(A_/32, DI_/32), blk, 0, stream>>>(att_img_k, wt1, DI_, A_);
  transpose_f32_bf16<<<dim3(N3U/32, DI_/32), blk, 0, stream>>>(kern + (size_t)DT_*N3U, wt2, DI_, N3U);
  transpose_f32_bf16<<<dim3(N3U/32, DT_/32), blk, 0, stream>>>(kern, wt3, DT_, N3U);
  build_wcat<<<dim3(U_), blk, 0, stream>>>(att_hid_k, att_hid_b, rec_kern, rec_bias, Wcat, bcat);

  // big GEMMs on MFMA (A operand converted fp32->bf16 during staging)
  // img_proj = img @ att_img_kernel + att_img_bias   [16384 x 512, K=2048] -> bf16
  gemm_a32_bt16_mfma<<<dim3(A_/128, (B_*L_)/128), blk, 0, stream>>>(
      img, wt1, att_img_b, img_proj, B_*L_, A_, DI_, 1);
  // imgW = img @ kernel[DT:]                         [16384 x 1536, K=2048] -> bf16
  gemm_a32_bt16_mfma<<<dim3(N3U/128, (B_*L_)/128), blk, 0, stream>>>(
      img, wt2, nullptr, imgW, B_*L_, N3U, DI_, 1);
  // text_proj = text @ kernel[:DT] + input_bias      [8192 x 1536, K=512] -> fp32
  gemm_a32_bt16_mfma<<<dim3(N3U/128, (B_*T_)/128), blk, 0, stream>>>(
      text, wt3, input_bias, text_proj, B_*T_, N3U, DT_, 0);

  // sequential recurrence
  for (int t = 0; t < T_; ++t) {
    // hm = h @ [att_hid_k | rec_kern] + [att_hid_b | rec_bias]   [256 x 2048, K=512]
    gemm_f32<<<dim3(2048/BN, B_/BM), blk, 0, stream>>>(h, Wcat, bcat, hm, B_, 2048, U_);
    attn_score<<<dim3(B_), blk, 0, stream>>>(img_proj, hm, att_v_k, attw);
    gru_step<<<dim3(B_), dim3(512), 0, stream>>>(imgW, attw, text_proj, hm, h, out, t);
  }
}

// Round 4
// 1765.372 us; speedup vs baseline: 3.7766x; 1.8475x over previous
//
#include <hip/hip_runtime.h>
#include <hip/hip_bf16.h>

// Problem dims (fixed by reference)
#define B_  256
#define L_  64
#define DI_ 2048
#define T_  32
#define DT_ 512
#define U_  512
#define A_  512
#define N3U 1536   // 3*U

typedef short short8 __attribute__((ext_vector_type(8)));   // 8 bf16 = 4 VGPRs
typedef float floatx4 __attribute__((ext_vector_type(4)));  // mfma acc

// fp32 -> bf16 round-to-nearest-even
__device__ __forceinline__ unsigned short f2bf(float f) {
  unsigned int u = __float_as_uint(f);
  u += 0x7fffu + ((u >> 16) & 1u);
  return (unsigned short)(u >> 16);
}
__device__ __forceinline__ float bf2f(unsigned short s) {
  return __uint_as_float(((unsigned int)s) << 16);
}
__device__ __forceinline__ float fast_tanh(float x) {
  x = fminf(fmaxf(x, -15.f), 15.f);
  float e = __expf(2.f * x);
  return (e - 1.f) / (e + 1.f);
}

// ---------------------------------------------------------------------------
// MFMA GEMM with fused A-conversion:
//   C[M,N] = A[M,K](fp32) @ Bt[N,K](bf16)^T (+bias), out fp32 or bf16.
// 128x128 tile, BK=32, 256 threads = 4 waves, each wave 64x64 sub-tile.
// LDS row stride 40 ushorts (pad 8): fragment ds_read_b128 at free 2-way.
// M%128==0, N%128==0, K%32==0.
// ---------------------------------------------------------------------------
__global__ __launch_bounds__(256) void gemm_a32_bt16_mfma(
    const float* __restrict__ A, const unsigned short* __restrict__ Bt,
    const float* __restrict__ bias, void* __restrict__ Cout,
    int M, int N, int K, int out_bf16) {
  __shared__ unsigned short As[128][40];
  __shared__ unsigned short Bs[128][40];
  const int tid  = threadIdx.x;
  const int wave = tid >> 6;
  const int lane = tid & 63;
  const int quad = lane >> 4;
  const int lr   = lane & 15;
  const int wrow = (wave >> 1) * 64;
  const int wcol = (wave & 1) * 64;
  const size_t bm = (size_t)blockIdx.y * 128;
  const size_t bn = (size_t)blockIdx.x * 128;

  const int sr = tid >> 2;          // staging row 0..63
  const int sc = (tid & 3) * 8;     // staging col (ushorts) 0,8,16,24

  floatx4 acc[4][4] = {};

  for (int k0 = 0; k0 < K; k0 += 32) {
#pragma unroll
    for (int it = 0; it < 2; ++it) {
      const int row = sr + it * 64;
      const float* ap = A + (bm + row) * (size_t)K + k0 + sc;
      float4 a0 = *(const float4*)(ap);
      float4 a1 = *(const float4*)(ap + 4);
      short8 pk;
      pk[0] = (short)f2bf(a0.x); pk[1] = (short)f2bf(a0.y);
      pk[2] = (short)f2bf(a0.z); pk[3] = (short)f2bf(a0.w);
      pk[4] = (short)f2bf(a1.x); pk[5] = (short)f2bf(a1.y);
      pk[6] = (short)f2bf(a1.z); pk[7] = (short)f2bf(a1.w);
      *(short8*)&As[row][sc] = pk;
      *(float4*)&Bs[row][sc] = *(const float4*)(Bt + (bn + row) * (size_t)K + k0 + sc);
    }
    __syncthreads();
    short8 af[4], bf[4];
#pragma unroll
    for (int mi = 0; mi < 4; ++mi) af[mi] = *(const short8*)&As[wrow + mi * 16 + lr][quad * 8];
#pragma unroll
    for (int ni = 0; ni < 4; ++ni) bf[ni] = *(const short8*)&Bs[wcol + ni * 16 + lr][quad * 8];
#pragma unroll
    for (int mi = 0; mi < 4; ++mi)
#pragma unroll
      for (int ni = 0; ni < 4; ++ni)
        acc[mi][ni] = __builtin_amdgcn_mfma_f32_16x16x32_bf16(af[mi], bf[ni], acc[mi][ni], 0, 0, 0);
    __syncthreads();
  }

  float* outf = (float*)Cout;
  unsigned short* outb = (unsigned short*)Cout;
#pragma unroll
  for (int mi = 0; mi < 4; ++mi) {
#pragma unroll
    for (int ni = 0; ni < 4; ++ni) {
      const size_t row0 = bm + wrow + mi * 16 + quad * 4;
      const size_t col  = bn + wcol + ni * 16 + lr;
      const float bsum = bias ? bias[col] : 0.f;
#pragma unroll
      for (int reg = 0; reg < 4; ++reg) {
        const float v = acc[mi][ni][reg] + bsum;
        if (out_bf16) outb[(row0 + reg) * (size_t)N + col] = f2bf(v);
        else          outf[(row0 + reg) * (size_t)N + col] = v;
      }
    }
  }
}

// ---------------------------------------------------------------------------
// small helpers
// ---------------------------------------------------------------------------
__global__ void zero_f32(float* __restrict__ p, int n) {
  int i = blockIdx.x * 256 + threadIdx.x;
  if (i < n) p[i] = 0.f;
}

// in[K,N] fp32 -> out[N,K] bf16 (tiled transpose). K%32==0, N%32==0.
__global__ __launch_bounds__(256) void transpose_f32_bf16(
    const float* __restrict__ in, unsigned short* __restrict__ outp, int K, int N) {
  __shared__ unsigned short tile[32][33];
  const int tid = threadIdx.x;
  const int tx = tid & 31, ty = tid >> 5;  // ty 0..7
  const int k0 = blockIdx.y * 32, n0 = blockIdx.x * 32;
#pragma unroll
  for (int i = 0; i < 4; ++i) {
    const int kk = ty + i * 8;
    tile[tx][kk] = f2bf(in[(size_t)(k0 + kk) * N + n0 + tx]);
  }
  __syncthreads();
#pragma unroll
  for (int i = 0; i < 4; ++i) {
    const int nn = ty + i * 8;
    outp[(size_t)(n0 + nn) * K + k0 + tx] = tile[nn][tx];
  }
}

// bcat[2048] = [att_hid_bias | rec_bias]
__global__ void build_bcat(const float* __restrict__ ahb,
                           const float* __restrict__ rb,
                           float* __restrict__ bcat) {
  int i = blockIdx.x * 256 + threadIdx.x;
  if (i < A_) bcat[i] = ahb[i];
  else if (i < A_ + N3U) bcat[i] = rb[i - A_];
}

// ---------------------------------------------------------------------------
// Fused per-step kernel: attention scores + softmax + combine + GRU gates.
// One block (512 threads = 8 waves) per batch element b.
//   phase A: score[l] = sum_a tanh(img_proj[b,l,a] + hproj[b,a]) * v[a]
//            (wave w handles l = w, w+8, ...; lane covers a = lane*8..+8)
//   softmax over L=64 in the first 64 threads -> aw[] in LDS
//   phase B: thread u (0..511) owns gate triple (u, 512+u, 1024+u):
//            mx = sum_l aw[l]*imgW[b,l,·] + text_proj ; GRU gate math.
// ---------------------------------------------------------------------------
__global__ __launch_bounds__(512) void attn_gru_step(
    const unsigned short* __restrict__ img_proj,  // [B,L,A] bf16
    const unsigned short* __restrict__ imgW,      // [B,L,3U] bf16
    const float* __restrict__ text_proj,          // [B,T,3U] fp32
    const float* __restrict__ hm,                 // [B,2048] = [hproj | mi]
    const float* __restrict__ vk,                 // [A]
    float* __restrict__ h,                        // [B,U] in/out
    float* __restrict__ out,                      // [B,T,U]
    int t) {
  const int b = blockIdx.x;
  const int tid = threadIdx.x;
  const int lane = tid & 63;
  const int wave = tid >> 6;   // 0..7
  __shared__ float sc[L_];
  __shared__ float aw[L_];

  // per-lane slice of hproj and v (a = lane*8 + j), reused for all 8 l's
  const float* hpg = hm + (size_t)b * 2048;   // hproj = cols [0,512)
  float hpv[8], vvv[8];
  {
    float4 h0 = *(const float4*)(hpg + lane * 8);
    float4 h1 = *(const float4*)(hpg + lane * 8 + 4);
    float4 v0 = *(const float4*)(vk + lane * 8);
    float4 v1 = *(const float4*)(vk + lane * 8 + 4);
    hpv[0]=h0.x; hpv[1]=h0.y; hpv[2]=h0.z; hpv[3]=h0.w;
    hpv[4]=h1.x; hpv[5]=h1.y; hpv[6]=h1.z; hpv[7]=h1.w;
    vvv[0]=v0.x; vvv[1]=v0.y; vvv[2]=v0.z; vvv[3]=v0.w;
    vvv[4]=v1.x; vvv[5]=v1.y; vvv[6]=v1.z; vvv[7]=v1.w;
  }

  // phase A: scores
#pragma unroll
  for (int i = 0; i < 8; ++i) {
    const int l = wave + i * 8;
    const unsigned short* ip = img_proj + ((size_t)b * L_ + l) * A_ + lane * 8;
    short8 v8 = *(const short8*)ip;
    float s = 0.f;
#pragma unroll
    for (int j = 0; j < 8; ++j) {
      s += fast_tanh(bf2f((unsigned short)v8[j]) + hpv[j]) * vvv[j];
    }
#pragma unroll
    for (int off = 32; off; off >>= 1) s += __shfl_down(s, off);
    if (lane == 0) sc[l] = s;
  }
  __syncthreads();

  // softmax over 64 regions
  if (tid < 64) {
    float x = sc[tid];
    float m = x;
#pragma unroll
    for (int off = 32; off; off >>= 1) m = fmaxf(m, __shfl_xor(m, off));
    float e = __expf(x - m);
    float ssum = e;
#pragma unroll
    for (int off = 32; off; off >>= 1) ssum += __shfl_xor(ssum, off);
    aw[tid] = e / ssum;
  }
  __syncthreads();

  // phase B: combine + gates (thread u owns gate triple)
  const int u = tid;
  const unsigned short* iw = imgW + (size_t)b * L_ * N3U + u;
  float s0 = 0.f, s1 = 0.f, s2 = 0.f;
#pragma unroll 8
  for (int l = 0; l < L_; ++l) {
    const float a = aw[l];
    const unsigned short* p = iw + l * N3U;
    s0 += a * bf2f(p[0]);
    s1 += a * bf2f(p[512]);
    s2 += a * bf2f(p[1024]);
  }
  const float* tp  = text_proj + ((size_t)b * T_ + t) * N3U;
  const float* mib = hm + (size_t)b * 2048 + 512;   // mi = cols [512,2048)
  const float xz = s0 + tp[u]        + mib[u];
  const float xr = s1 + tp[512 + u]  + mib[512 + u];
  const float xh = s2 + tp[1024 + u];
  const float rh = mib[1024 + u];
  const float z = 1.f / (1.f + __expf(-xz));
  const float r = 1.f / (1.f + __expf(-xr));
  const float hh = fast_tanh(xh + r * rh);
  const float hn = z * h[b * U_ + u] + (1.f - z) * hh;
  h[b * U_ + u] = hn;
  out[((size_t)b * T_ + t) * U_ + u] = hn;
}

// ---------------------------------------------------------------------------
// launch
// ---------------------------------------------------------------------------
extern "C" void kernel_launch(void* const* d_in, const int* in_sizes, int n_in,
                              void* d_out, int out_size, void* d_ws, size_t ws_size,
                              hipStream_t stream) {
  const float* img        = (const float*)d_in[0];   // [B,L,DI]
  const float* text       = (const float*)d_in[1];   // [B,T,DT]
  const float* kern       = (const float*)d_in[2];   // [DT+DI, 3U]
  const float* input_bias = (const float*)d_in[3];   // [3U]
  const float* rec_kern   = (const float*)d_in[4];   // [U,3U]
  const float* rec_bias   = (const float*)d_in[5];   // [3U]
  const float* att_img_k  = (const float*)d_in[6];   // [DI,A]
  const float* att_img_b  = (const float*)d_in[7];   // [A]
  const float* att_hid_k  = (const float*)d_in[8];   // [U,A]
  const float* att_hid_b  = (const float*)d_in[9];   // [A]
  const float* att_v_k    = (const float*)d_in[10];  // [A,1]
  // d_in[11] = att_v_bias — cancels in softmax.
  float* out = (float*)d_out;

  // workspace layout (bytes, 256-aligned). NO ALIASING. ~132 MB total.
  char* ws = (char*)d_ws;
  size_t off = 0;
  auto alloc = [&](size_t bytes) { char* p = ws + off; off += (bytes + 255) & ~(size_t)255; return p; };
  unsigned short* img_proj = (unsigned short*)alloc((size_t)B_*L_*A_*2);   // 16.8 MB bf16
  unsigned short* imgW     = (unsigned short*)alloc((size_t)B_*L_*N3U*2);  // 50.3 MB bf16
  float*          text_proj= (float*)         alloc((size_t)B_*T_*N3U*4);  // 50.3 MB fp32
  unsigned short* wt1      = (unsigned short*)alloc((size_t)A_*DI_*2);     // att_img_k^T
  unsigned short* wt2      = (unsigned short*)alloc((size_t)N3U*DI_*2);    // kern[DT:]^T
  unsigned short* wt3      = (unsigned short*)alloc((size_t)N3U*DT_*2);    // kern[:DT]^T
  unsigned short* wcatT    = (unsigned short*)alloc((size_t)2048*U_*2);    // [ahk|rk]^T bf16 [2048,512]
  float*          bcat     = (float*)         alloc(2048*4);
  float*          h        = (float*)         alloc((size_t)B_*U_*4);
  float*          hm       = (float*)         alloc((size_t)B_*2048*4);

  dim3 blk(256);

  zero_f32<<<dim3((B_*U_ + 255) / 256), blk, 0, stream>>>(h, B_*U_);

  // one-time weight transposes (fp32 -> bf16^T)
  transpose_f32_bf16<<<dim3(A_/32, DI_/32), blk, 0, stream>>>(att_img_k, wt1, DI_, A_);
  transpose_f32_bf16<<<dim3(N3U/32, DI_/32), blk, 0, stream>>>(kern + (size_t)DT_*N3U, wt2, DI_, N3U);
  transpose_f32_bf16<<<dim3(N3U/32, DT_/32), blk, 0, stream>>>(kern, wt3, DT_, N3U);
  // wcatT rows [0,512) = att_hid_k^T ; rows [512,2048) = rec_kern^T
  transpose_f32_bf16<<<dim3(A_/32, U_/32), blk, 0, stream>>>(att_hid_k, wcatT, U_, A_);
  transpose_f32_bf16<<<dim3(N3U/32, U_/32), blk, 0, stream>>>(rec_kern, wcatT + (size_t)A_*U_, U_, N3U);
  build_bcat<<<dim3(8), blk, 0, stream>>>(att_hid_b, rec_bias, bcat);

  // big GEMMs on MFMA (A operand converted fp32->bf16 during staging)
  gemm_a32_bt16_mfma<<<dim3(A_/128, (B_*L_)/128), blk, 0, stream>>>(
      img, wt1, att_img_b, img_proj, B_*L_, A_, DI_, 1);
  gemm_a32_bt16_mfma<<<dim3(N3U/128, (B_*L_)/128), blk, 0, stream>>>(
      img, wt2, nullptr, imgW, B_*L_, N3U, DI_, 1);
  gemm_a32_bt16_mfma<<<dim3(N3U/128, (B_*T_)/128), blk, 0, stream>>>(
      text, wt3, input_bias, text_proj, B_*T_, N3U, DT_, 0);

  // sequential recurrence: 2 launches/step
  for (int t = 0; t < T_; ++t) {
    // hm = h @ [att_hid_k | rec_kern] + [att_hid_b | rec_bias]  [256 x 2048, K=512]
    gemm_a32_bt16_mfma<<<dim3(2048/128, B_/128), blk, 0, stream>>>(
        h, wcatT, bcat, hm, B_, 2048, U_, 0);
    attn_gru_step<<<dim3(B_), dim3(512), 0, stream>>>(
        img_proj, imgW, text_proj, hm, att_v_k, h, out, t);
  }
}